// Round 2
// baseline (78543.860 us; speedup 1.0000x reference)
//
#include <hip/hip_runtime.h>
#include <hip/hip_bf16.h>

#define HDIM 1024
#define VDIM 512
#define TLEN 256
#define BATCH 256
#define FPDIM 2048
#define H3 3072

struct GemmArgs {
  const float* A;      // amode 0: fp32 A [M,K]
  const float* emb;    // amode 1: emb table [V,K]
  const int* target;   // amode 1: [B,T] int tokens
  const float* W;      // [N,K] row-major (K contiguous)
  const float* bias;   // [N]
  float* C;            // fp32 out [M,ldc]
  float* C2;           // optional duplicate out
  int ldc;
  int K;
  int t;               // step (amode 1)
  int amode;           // 0 = fp32 A, 1 = embed-gather+relu
  int relu;            // relu on output
};

#define BM 64
#define BN 64
#define BK 16
#define LDP 68  // 64 + 4 pad: keeps float4 16B-aligned, 2-way-max bank aliasing (free)

__global__ __launch_bounds__(256) void gemm_bt(GemmArgs g0, GemmArgs g1) {
  GemmArgs g = (blockIdx.z == 0) ? g0 : g1;
  __shared__ float As[BK][LDP];
  __shared__ float Ws[BK][LDP];
  __shared__ int toks[BM];
  const int tid = threadIdx.x;
  const int tx = tid & 15, ty = tid >> 4;
  const int m0 = blockIdx.y * BM, n0 = blockIdx.x * BN;

  if (g.amode == 1 && tid < BM) {
    int m = m0 + tid;
    toks[tid] = (g.t == 0) ? 0 : g.target[m * TLEN + g.t - 1];
  }
  __syncthreads();

  float acc[4][4] = {{0.f, 0.f, 0.f, 0.f}};
  const int K = g.K;
  const int nk = K / BK;
  for (int kb = 0; kb < nk; ++kb) {
    const int k0 = kb * BK;
#pragma unroll
    for (int i = 0; i < 4; ++i) {
      int idx = tid + i * 256;         // 64x16 tile, k fastest
      int ml = idx >> 4, kl = idx & 15;
      float a;
      if (g.amode == 0) {
        a = g.A[(size_t)(m0 + ml) * K + k0 + kl];
      } else {
        a = g.emb[(size_t)toks[ml] * K + k0 + kl];
        a = fmaxf(a, 0.f);             // x = relu(emb[tok])
      }
      As[kl][ml] = a;
      Ws[kl][ml] = g.W[(size_t)(n0 + ml) * K + k0 + kl];
    }
    __syncthreads();
#pragma unroll
    for (int k = 0; k < BK; ++k) {
      float4 av = *(const float4*)&As[k][ty * 4];
      float4 wv = *(const float4*)&Ws[k][tx * 4];
      float a[4] = {av.x, av.y, av.z, av.w};
      float w[4] = {wv.x, wv.y, wv.z, wv.w};
#pragma unroll
      for (int i = 0; i < 4; ++i)
#pragma unroll
        for (int j = 0; j < 4; ++j)
          acc[i][j] = fmaf(a[i], w[j], acc[i][j]);
    }
    __syncthreads();
  }

#pragma unroll
  for (int i = 0; i < 4; ++i) {
    int m = m0 + ty * 4 + i;
#pragma unroll
    for (int j = 0; j < 4; ++j) {
      int n = n0 + tx * 4 + j;
      float v = acc[i][j] + g.bias[n];
      if (g.relu) v = fmaxf(v, 0.f);
      g.C[(size_t)m * g.ldc + n] = v;
      if (g.C2) g.C2[(size_t)m * g.ldc + n] = v;
    }
  }
}

// GRU gate combine: h = (1-z)*n + z*h, one thread per (b,i)
__global__ __launch_bounds__(256) void gru_combine(const float* __restrict__ gi,
                                                   const float* __restrict__ gh,
                                                   float* __restrict__ h) {
  int idx = blockIdx.x * 256 + threadIdx.x;  // over BATCH*HDIM
  int b = idx >> 10, i = idx & 1023;
  size_t base = (size_t)b * H3;
  float ir = gi[base + i], iz = gi[base + HDIM + i], inn = gi[base + 2 * HDIM + i];
  float hr = gh[base + i], hz = gh[base + HDIM + i], hn = gh[base + 2 * HDIM + i];
  float r = 1.f / (1.f + expf(-(ir + hr)));
  float z = 1.f / (1.f + expf(-(iz + hz)));
  float n = tanhf(inn + r * hn);
  h[idx] = (1.f - z) * n + z * h[idx];
}

// Fused output projection + log_softmax. One block (256 thr) per batch row.
__global__ __launch_bounds__(256) void outproj_softmax(const float* __restrict__ h1,
                                                       const float* __restrict__ Wo,
                                                       const float* __restrict__ bo,
                                                       float* __restrict__ out, int t) {
  const int b = blockIdx.x;
  const int tid = threadIdx.x;
  __shared__ float hs[HDIM];
  __shared__ float logits[VDIM];
  __shared__ float smax[4], ssum[4];

  for (int i = tid; i < HDIM; i += 256) hs[i] = h1[(size_t)b * HDIM + i];
  __syncthreads();

  for (int vv = tid; vv < VDIM; vv += 256) {
    const float4* w4 = (const float4*)(Wo + (size_t)vv * HDIM);
    float s = 0.f;
#pragma unroll 4
    for (int k4 = 0; k4 < HDIM / 4; ++k4) {
      float4 w = w4[k4];
      const float* hp = &hs[k4 * 4];
      s = fmaf(hp[0], w.x, s);
      s = fmaf(hp[1], w.y, s);
      s = fmaf(hp[2], w.z, s);
      s = fmaf(hp[3], w.w, s);
    }
    logits[vv] = s + bo[vv];
  }
  __syncthreads();

  float lm = -1e30f;
  for (int vv = tid; vv < VDIM; vv += 256) lm = fmaxf(lm, logits[vv]);
#pragma unroll
  for (int o = 32; o > 0; o >>= 1) lm = fmaxf(lm, __shfl_down(lm, o));
  if ((tid & 63) == 0) smax[tid >> 6] = lm;
  __syncthreads();
  float bmax = fmaxf(fmaxf(smax[0], smax[1]), fmaxf(smax[2], smax[3]));

  float ls = 0.f;
  for (int vv = tid; vv < VDIM; vv += 256) ls += expf(logits[vv] - bmax);
#pragma unroll
  for (int o = 32; o > 0; o >>= 1) ls += __shfl_down(ls, o);
  if ((tid & 63) == 0) ssum[tid >> 6] = ls;
  __syncthreads();
  float lse = bmax + logf(ssum[0] + ssum[1] + ssum[2] + ssum[3]);

  float* orow = out + ((size_t)b * TLEN + t) * VDIM;
  for (int vv = tid; vv < VDIM; vv += 256) orow[vv] = logits[vv] - lse;
}

__global__ __launch_bounds__(256) void write_hfinal(const float* __restrict__ h0,
                                                    const float* __restrict__ h1,
                                                    float* __restrict__ out) {
  int idx = blockIdx.x * 256 + threadIdx.x;  // over 2*B*H
  const int BH = BATCH * HDIM;
  out[idx] = (idx < BH) ? h0[idx] : h1[idx - BH];
}

extern "C" void kernel_launch(void* const* d_in, const int* in_sizes, int n_in,
                              void* d_out, int out_size, void* d_ws, size_t ws_size,
                              hipStream_t stream) {
  // d_in[0] = encoder_outputs (unused by the reference computation)
  const float* fps    = (const float*)d_in[1];   // [B,FP]
  const int* target   = (const int*)d_in[2];     // [B,T]
  const float* emb    = (const float*)d_in[3];   // [V,H]
  const float* Wc     = (const float*)d_in[4];   // [H,FP]
  const float* bc     = (const float*)d_in[5];   // [H]
  const float* W_ih   = (const float*)d_in[6];   // [2,3H,H]
  const float* W_hh   = (const float*)d_in[7];   // [2,3H,H]
  const float* b_ih   = (const float*)d_in[8];   // [2,3H]
  const float* b_hh   = (const float*)d_in[9];   // [2,3H]
  const float* Wo     = (const float*)d_in[10];  // [V,H]
  const float* bo     = (const float*)d_in[11];  // [V]
  float* out = (float*)d_out;

  float* ws = (float*)d_ws;
  const int BH = BATCH * HDIM;
  float* h0  = ws;               // [B,H]
  float* h1  = h0 + BH;          // [B,H]
  float* gi0 = h1 + BH;          // [B,3H]
  float* gh0 = gi0 + BATCH * H3;
  float* gi1 = gh0 + BATCH * H3;
  float* gh1 = gi1 + BATCH * H3;

  // h0 = h1 = relu(fingerprints @ Wc^T + bc)
  GemmArgs ginit;
  ginit.A = fps; ginit.emb = nullptr; ginit.target = nullptr;
  ginit.W = Wc; ginit.bias = bc; ginit.C = h0; ginit.C2 = h1;
  ginit.ldc = HDIM; ginit.K = FPDIM; ginit.t = 0; ginit.amode = 0; ginit.relu = 1;
  gemm_bt<<<dim3(HDIM / BN, BATCH / BM, 1), 256, 0, stream>>>(ginit, ginit);

  for (int t = 0; t < TLEN; ++t) {
    // layer 0 gates: gi0 = relu(emb[tok]) @ W_ih0^T + b_ih0 ; gh0 = h0 @ W_hh0^T + b_hh0
    GemmArgs a0, a1;
    a0.A = nullptr; a0.emb = emb; a0.target = target;
    a0.W = W_ih; a0.bias = b_ih; a0.C = gi0; a0.C2 = nullptr;
    a0.ldc = H3; a0.K = HDIM; a0.t = t; a0.amode = 1; a0.relu = 0;
    a1.A = h0; a1.emb = nullptr; a1.target = nullptr;
    a1.W = W_hh; a1.bias = b_hh; a1.C = gh0; a1.C2 = nullptr;
    a1.ldc = H3; a1.K = HDIM; a1.t = t; a1.amode = 0; a1.relu = 0;
    gemm_bt<<<dim3(H3 / BN, BATCH / BM, 2), 256, 0, stream>>>(a0, a1);
    gru_combine<<<BH / 256, 256, 0, stream>>>(gi0, gh0, h0);

    // layer 1 gates: gi1 = h0 @ W_ih1^T + b_ih1 ; gh1 = h1 @ W_hh1^T + b_hh1
    GemmArgs c0, c1;
    c0.A = h0; c0.emb = nullptr; c0.target = nullptr;
    c0.W = W_ih + (size_t)H3 * HDIM; c0.bias = b_ih + H3; c0.C = gi1; c0.C2 = nullptr;
    c0.ldc = H3; c0.K = HDIM; c0.t = t; c0.amode = 0; c0.relu = 0;
    c1.A = h1; c1.emb = nullptr; c1.target = nullptr;
    c1.W = W_hh + (size_t)H3 * HDIM; c1.bias = b_hh + H3; c1.C = gh1; c1.C2 = nullptr;
    c1.ldc = H3; c1.K = HDIM; c1.t = t; c1.amode = 0; c1.relu = 0;
    gemm_bt<<<dim3(H3 / BN, BATCH / BM, 2), 256, 0, stream>>>(c0, c1);
    gru_combine<<<BH / 256, 256, 0, stream>>>(gi1, gh1, h1);

    // logits + log_softmax -> out[b, t, :]
    outproj_softmax<<<BATCH, 256, 0, stream>>>(h1, Wo, bo, out, t);
  }

  // h_final: [L=2, B, H] appended after log_probs
  write_hfinal<<<2 * BH / 256, 256, 0, stream>>>(h0, h1, out + (size_t)BATCH * TLEN * VDIM);
}

// Round 3
// 21560.596 us; speedup vs baseline: 3.6429x; 3.6429x over previous
//
#include <hip/hip_runtime.h>
#include <hip/hip_bf16.h>

#define HDIM 1024
#define VDIM 512
#define TLEN 256
#define BATCH 256
#define FPDIM 2048
#define H3 3072
#define NB0 256   // gemm-role blocks per step kernel: 8 batch-tiles x 32 h-tiles

typedef __hip_bfloat16 bf16;
typedef __attribute__((ext_vector_type(8))) short s8v;    // 8 bf16 (4 VGPRs)
typedef __attribute__((ext_vector_type(4))) float f4v;    // MFMA C/D

__device__ __forceinline__ float bs2f(unsigned short s) {
  union { unsigned u; float f; } c; c.u = ((unsigned)s) << 16; return c.f;
}
__device__ __forceinline__ f4v mfma_bf16(s8v a, s8v b, f4v c) {
  return __builtin_amdgcn_mfma_f32_16x16x32_bf16(a, b, c, 0, 0, 0);
}
__device__ __forceinline__ s8v ld8(const bf16* p) { return *(const s8v*)p; }
__device__ __forceinline__ float sigf(float x) { return 1.f / (1.f + expf(-x)); }

// ---------------- fp32 -> bf16 convert ----------------
__global__ __launch_bounds__(256) void f32_to_bf16(const float* __restrict__ src,
                                                   bf16* __restrict__ dst, int n) {
  int i = blockIdx.x * 256 + threadIdx.x;
  if (i < n) dst[i] = __float2bfloat16(src[i]);
}

// ---------------- fp32 tile GEMM (one-time: init hidden + gi0 table) ----------------
struct GemmArgs {
  const float* A;      // [M,K]
  const float* W;      // [N,K]
  const float* bias;   // [N]
  float* C;            // fp32 out [M,ldc]
  float* C2;           // optional dup
  bf16* Cb;            // optional bf16 dup
  bf16* Cb2;           // optional bf16 dup
  int ldc;
  int K;
  int reluA;           // relu on A
  int reluC;           // relu on C
};

#define BM 64
#define BN 64
#define BK 16
#define LDP 68

__global__ __launch_bounds__(256) void gemm_bt(GemmArgs g) {
  __shared__ float As[BK][LDP];
  __shared__ float Ws[BK][LDP];
  const int tid = threadIdx.x;
  const int tx = tid & 15, ty = tid >> 4;
  const int m0 = blockIdx.y * BM, n0 = blockIdx.x * BN;

  float acc[4][4] = {{0.f, 0.f, 0.f, 0.f}};
  const int K = g.K;
  const int nk = K / BK;
  for (int kb = 0; kb < nk; ++kb) {
    const int k0 = kb * BK;
#pragma unroll
    for (int i = 0; i < 4; ++i) {
      int idx = tid + i * 256;
      int ml = idx >> 4, kl = idx & 15;
      float a = g.A[(size_t)(m0 + ml) * K + k0 + kl];
      if (g.reluA) a = fmaxf(a, 0.f);
      As[kl][ml] = a;
      Ws[kl][ml] = g.W[(size_t)(n0 + ml) * K + k0 + kl];
    }
    __syncthreads();
#pragma unroll
    for (int k = 0; k < BK; ++k) {
      float4 av = *(const float4*)&As[k][ty * 4];
      float4 wv = *(const float4*)&Ws[k][tx * 4];
      float a[4] = {av.x, av.y, av.z, av.w};
      float w[4] = {wv.x, wv.y, wv.z, wv.w};
#pragma unroll
      for (int i = 0; i < 4; ++i)
#pragma unroll
        for (int j = 0; j < 4; ++j)
          acc[i][j] = fmaf(a[i], w[j], acc[i][j]);
    }
    __syncthreads();
  }
#pragma unroll
  for (int i = 0; i < 4; ++i) {
    int m = m0 + ty * 4 + i;
#pragma unroll
    for (int j = 0; j < 4; ++j) {
      int n = n0 + tx * 4 + j;
      float v = acc[i][j] + g.bias[n];
      if (g.reluC) v = fmaxf(v, 0.f);
      g.C[(size_t)m * g.ldc + n] = v;
      if (g.C2) g.C2[(size_t)m * g.ldc + n] = v;
      if (g.Cb) g.Cb[(size_t)m * g.ldc + n] = __float2bfloat16(v);
      if (g.Cb2) g.Cb2[(size_t)m * g.ldc + n] = __float2bfloat16(v);
    }
  }
}

// ---------------- fused output projection + log_softmax (device fn) ----------------
__device__ void outproj_block(int b, const float* __restrict__ h1,
                              const bf16* __restrict__ Wo,
                              const float* __restrict__ bo,
                              float* __restrict__ out, int t) {
  const int tid = threadIdx.x;
  __shared__ float hs[HDIM];
  __shared__ float logits[VDIM];
  __shared__ float red[4];

  for (int i = tid; i < HDIM; i += 256) hs[i] = h1[(size_t)b * HDIM + i];
  __syncthreads();

  for (int vv = tid; vv < VDIM; vv += 256) {
    const bf16* wrow = Wo + (size_t)vv * HDIM;
    float s = 0.f;
#pragma unroll 4
    for (int k8 = 0; k8 < HDIM / 8; ++k8) {
      s8v w = ld8(wrow + k8 * 8);
      const float* hp = &hs[k8 * 8];
#pragma unroll
      for (int j = 0; j < 8; ++j)
        s = fmaf(hp[j], bs2f((unsigned short)w[j]), s);
    }
    logits[vv] = s + bo[vv];
  }
  __syncthreads();

  float lm = -1e30f;
  for (int vv = tid; vv < VDIM; vv += 256) lm = fmaxf(lm, logits[vv]);
#pragma unroll
  for (int o = 32; o > 0; o >>= 1) lm = fmaxf(lm, __shfl_down(lm, o));
  if ((tid & 63) == 0) red[tid >> 6] = lm;
  __syncthreads();
  float bmax = fmaxf(fmaxf(red[0], red[1]), fmaxf(red[2], red[3]));
  __syncthreads();

  float ls = 0.f;
  for (int vv = tid; vv < VDIM; vv += 256) ls += expf(logits[vv] - bmax);
#pragma unroll
  for (int o = 32; o > 0; o >>= 1) ls += __shfl_down(ls, o);
  if ((tid & 63) == 0) red[tid >> 6] = ls;
  __syncthreads();
  float lse = bmax + logf(red[0] + red[1] + red[2] + red[3]);

  float* orow = out + ((size_t)b * TLEN + t) * VDIM;
  for (int vv = tid; vv < VDIM; vv += 256) orow[vv] = logits[vv] - lse;
}

__global__ __launch_bounds__(256) void outproj_final(const float* __restrict__ h1,
                                                     const bf16* __restrict__ Wo,
                                                     const float* __restrict__ bo,
                                                     float* __restrict__ out, int t) {
  outproj_block(blockIdx.x, h1, Wo, bo, out, t);
}

// ---------------- step kernels (MFMA 16x16x32 bf16) ----------------
// Frag layouts (m89/m91-verified): A/B: [idx=lane&15][k=(lane>>4)*8+j]; C/D: col=lane&15, row=(lane>>4)*4+reg.

struct Step0Args {
  const bf16* hA16;     // h0_cur bf16 [B,H]
  const float* hA;      // h0_cur fp32
  const bf16* Whh;      // W_hh0 bf16 [3H,H]
  const float* bhh;     // b_hh0
  const float* table;   // gi0 table fp32 [V,3H] (includes b_ih0, relu(emb))
  const int* target;    // [B,T]
  float* hOut;          // h0_nxt fp32
  bf16* hOut16;         // h0_nxt bf16
  int t;
  // piggybacked outproj of step t-1:
  const float* h1;      // h1_cur fp32
  const bf16* Wo16;
  const float* bo;
  float* out;
  int t_out;            // t-1; <0 -> skip
};

__global__ __launch_bounds__(256) void step_layer0(Step0Args g) {
  if (blockIdx.x >= NB0) {
    if (g.t_out >= 0)
      outproj_block(blockIdx.x - NB0, g.h1, g.Wo16, g.bo, g.out, g.t_out);
    return;
  }
  const int blk = blockIdx.x;
  const int m0 = (blk >> 5) << 5;          // batch tile (8)
  const int n0 = (blk & 31) << 5;          // h tile (32)
  const int tid = threadIdx.x;
  const int w = tid >> 6, ln = tid & 63;
  const int l15 = ln & 15, quad = ln >> 4;
  const int mt = m0 + ((w & 1) << 4);
  const int nt = n0 + ((w >> 1) << 4);

  const bf16* pa = g.hA16 + (size_t)(mt + l15) * HDIM + quad * 8;
  const bf16* pb0 = g.Whh + (size_t)(nt + l15) * HDIM + quad * 8;
  const bf16* pb1 = pb0 + (size_t)1024 * HDIM;
  const bf16* pb2 = pb1 + (size_t)1024 * HDIM;

  f4v a0 = {0.f, 0.f, 0.f, 0.f}, a1 = a0, a2 = a0;
#pragma unroll 8
  for (int k = 0; k < HDIM; k += 32) {
    s8v A = ld8(pa + k);
    a0 = mfma_bf16(A, ld8(pb0 + k), a0);
    a1 = mfma_bf16(A, ld8(pb1 + k), a1);
    a2 = mfma_bf16(A, ld8(pb2 + k), a2);
  }

  const int n = nt + l15;
  const float bhr = g.bhh[n], bhz = g.bhh[n + 1024], bhn = g.bhh[n + 2048];
#pragma unroll
  for (int r = 0; r < 4; ++r) {
    int m = mt + quad * 4 + r;
    int tok = (g.t == 0) ? 0 : g.target[m * TLEN + g.t - 1];
    const float* trow = g.table + (size_t)tok * H3;
    float ir = trow[n], iz = trow[n + 1024], inn = trow[n + 2048];
    float rr = sigf(ir + a0[r] + bhr);
    float zz = sigf(iz + a1[r] + bhz);
    float nn = tanhf(inn + rr * (a2[r] + bhn));
    float hv = (1.f - zz) * nn + zz * g.hA[(size_t)m * HDIM + n];
    g.hOut[(size_t)m * HDIM + n] = hv;
    g.hOut16[(size_t)m * HDIM + n] = __float2bfloat16(hv);
  }
}

struct Step1Args {
  const bf16* x16;      // h0_nxt bf16 (layer-1 input)
  const bf16* hB16;     // h1_cur bf16
  const float* hB;      // h1_cur fp32
  const bf16* Wih;      // W_ih1 bf16 [3H,H]
  const bf16* Whh;      // W_hh1 bf16 [3H,H]
  const float* bih;
  const float* bhh;
  float* hOut;          // h1_nxt fp32
  bf16* hOut16;
};

__global__ __launch_bounds__(256) void step_layer1(Step1Args g) {
  const int blk = blockIdx.x;
  const int m0 = (blk >> 5) << 5;
  const int n0 = (blk & 31) << 5;
  const int tid = threadIdx.x;
  const int w = tid >> 6, ln = tid & 63;
  const int l15 = ln & 15, quad = ln >> 4;
  const int mt = m0 + ((w & 1) << 4);
  const int nt = n0 + ((w >> 1) << 4);

  const bf16* px = g.x16 + (size_t)(mt + l15) * HDIM + quad * 8;
  const bf16* ph = g.hB16 + (size_t)(mt + l15) * HDIM + quad * 8;
  const bf16* pir = g.Wih + (size_t)(nt + l15) * HDIM + quad * 8;
  const bf16* piz = pir + (size_t)1024 * HDIM;
  const bf16* pin = piz + (size_t)1024 * HDIM;
  const bf16* phr = g.Whh + (size_t)(nt + l15) * HDIM + quad * 8;
  const bf16* phz = phr + (size_t)1024 * HDIM;
  const bf16* phn = phz + (size_t)1024 * HDIM;

  f4v ar = {0.f, 0.f, 0.f, 0.f}, az = ar, ain = ar, ahn = ar;
#pragma unroll 4
  for (int k = 0; k < HDIM; k += 32) {
    s8v A0 = ld8(px + k);
    s8v A1 = ld8(ph + k);
    ar = mfma_bf16(A0, ld8(pir + k), ar);
    ar = mfma_bf16(A1, ld8(phr + k), ar);
    az = mfma_bf16(A0, ld8(piz + k), az);
    az = mfma_bf16(A1, ld8(phz + k), az);
    ain = mfma_bf16(A0, ld8(pin + k), ain);
    ahn = mfma_bf16(A1, ld8(phn + k), ahn);
  }

  const int n = nt + l15;
  const float br = g.bih[n] + g.bhh[n];
  const float bz = g.bih[n + 1024] + g.bhh[n + 1024];
  const float bin = g.bih[n + 2048], bhn = g.bhh[n + 2048];
#pragma unroll
  for (int r = 0; r < 4; ++r) {
    int m = mt + quad * 4 + r;
    float rr = sigf(ar[r] + br);
    float zz = sigf(az[r] + bz);
    float nn = tanhf(ain[r] + bin + rr * (ahn[r] + bhn));
    float hv = (1.f - zz) * nn + zz * g.hB[(size_t)m * HDIM + n];
    g.hOut[(size_t)m * HDIM + n] = hv;
    g.hOut16[(size_t)m * HDIM + n] = __float2bfloat16(hv);
  }
}

__global__ __launch_bounds__(256) void write_hfinal(const float* __restrict__ h0,
                                                    const float* __restrict__ h1,
                                                    float* __restrict__ out) {
  int idx = blockIdx.x * 256 + threadIdx.x;
  const int BH = BATCH * HDIM;
  out[idx] = (idx < BH) ? h0[idx] : h1[idx - BH];
}

extern "C" void kernel_launch(void* const* d_in, const int* in_sizes, int n_in,
                              void* d_out, int out_size, void* d_ws, size_t ws_size,
                              hipStream_t stream) {
  const float* fps    = (const float*)d_in[1];
  const int* target   = (const int*)d_in[2];
  const float* emb    = (const float*)d_in[3];
  const float* Wc     = (const float*)d_in[4];
  const float* bc     = (const float*)d_in[5];
  const float* W_ih   = (const float*)d_in[6];   // [2,3H,H]
  const float* W_hh   = (const float*)d_in[7];
  const float* b_ih   = (const float*)d_in[8];
  const float* b_hh   = (const float*)d_in[9];
  const float* Wo     = (const float*)d_in[10];
  const float* bo     = (const float*)d_in[11];
  float* out = (float*)d_out;

  const int BH = BATCH * HDIM;
  const size_t WN = (size_t)H3 * HDIM;          // 3.1M elems per gate matrix

  char* p = (char*)d_ws;
  float* h0a = (float*)p;  p += (size_t)BH * 4;
  float* h0b = (float*)p;  p += (size_t)BH * 4;
  float* h1a = (float*)p;  p += (size_t)BH * 4;
  float* h1b = (float*)p;  p += (size_t)BH * 4;
  float* table = (float*)p; p += (size_t)VDIM * H3 * 4;
  bf16* h0a16 = (bf16*)p;  p += (size_t)BH * 2;
  bf16* h0b16 = (bf16*)p;  p += (size_t)BH * 2;
  bf16* h1a16 = (bf16*)p;  p += (size_t)BH * 2;
  bf16* h1b16 = (bf16*)p;  p += (size_t)BH * 2;
  bf16* Whh0_16 = (bf16*)p; p += WN * 2;
  bf16* Wih1_16 = (bf16*)p; p += WN * 2;
  bf16* Whh1_16 = (bf16*)p; p += WN * 2;
  bf16* Wo16 = (bf16*)p;   p += (size_t)VDIM * HDIM * 2;

  // one-time conversions (every call; ws is re-poisoned)
  {
    int n = (int)WN;
    int nb = (n + 255) / 256;
    f32_to_bf16<<<nb, 256, 0, stream>>>(W_hh, Whh0_16, n);
    f32_to_bf16<<<nb, 256, 0, stream>>>(W_ih + WN, Wih1_16, n);
    f32_to_bf16<<<nb, 256, 0, stream>>>(W_hh + WN, Whh1_16, n);
    int nwo = VDIM * HDIM;
    f32_to_bf16<<<(nwo + 255) / 256, 256, 0, stream>>>(Wo, Wo16, nwo);
  }

  // h0 = h1 = relu(fps @ Wc^T + bc), fp32 + bf16 copies
  {
    GemmArgs a;
    a.A = fps; a.W = Wc; a.bias = bc;
    a.C = h0a; a.C2 = h1a; a.Cb = h0a16; a.Cb2 = h1a16;
    a.ldc = HDIM; a.K = FPDIM; a.reluA = 0; a.reluC = 1;
    gemm_bt<<<dim3(HDIM / BN, BATCH / BM), 256, 0, stream>>>(a);
  }
  // gi0 table = relu(emb) @ W_ih0^T + b_ih0   [V, 3H]
  {
    GemmArgs a;
    a.A = emb; a.W = W_ih; a.bias = b_ih;
    a.C = table; a.C2 = nullptr; a.Cb = nullptr; a.Cb2 = nullptr;
    a.ldc = H3; a.K = HDIM; a.reluA = 1; a.reluC = 0;
    gemm_bt<<<dim3(H3 / BN, VDIM / BM), 256, 0, stream>>>(a);
  }

  float *h0c = h0a, *h0n = h0b, *h1c = h1a, *h1n = h1b;
  bf16 *h0c16 = h0a16, *h0n16 = h0b16, *h1c16 = h1a16, *h1n16 = h1b16;

  for (int t = 0; t < TLEN; ++t) {
    Step0Args s0;
    s0.hA16 = h0c16; s0.hA = h0c;
    s0.Whh = Whh0_16; s0.bhh = b_hh;
    s0.table = table; s0.target = target;
    s0.hOut = h0n; s0.hOut16 = h0n16; s0.t = t;
    s0.h1 = h1c; s0.Wo16 = Wo16; s0.bo = bo; s0.out = out; s0.t_out = t - 1;
    step_layer0<<<NB0 + BATCH, 256, 0, stream>>>(s0);

    Step1Args s1;
    s1.x16 = h0n16; s1.hB16 = h1c16; s1.hB = h1c;
    s1.Wih = Wih1_16; s1.Whh = Whh1_16;
    s1.bih = b_ih + H3; s1.bhh = b_hh + H3;
    s1.hOut = h1n; s1.hOut16 = h1n16;
    step_layer1<<<NB0, 256, 0, stream>>>(s1);

    // ping-pong
    float* tf;  bf16* tb;
    tf = h0c; h0c = h0n; h0n = tf;  tb = h0c16; h0c16 = h0n16; h0n16 = tb;
    tf = h1c; h1c = h1n; h1n = tf;  tb = h1c16; h1c16 = h1n16; h1n16 = tb;
  }

  // last step's output projection + final hidden state
  outproj_final<<<BATCH, 256, 0, stream>>>(h1c, Wo16, bo, out, TLEN - 1);
  write_hfinal<<<2 * BH / 256, 256, 0, stream>>>(h0c, h1c, out + (size_t)BATCH * TLEN * VDIM);
}

// Round 4
// 15997.293 us; speedup vs baseline: 4.9098x; 1.3478x over previous
//
#include <hip/hip_runtime.h>
#include <hip/hip_bf16.h>

#define HDIM 1024
#define VDIM 512
#define TLEN 256
#define BATCH 256
#define FPDIM 2048
#define H3 3072

typedef __hip_bfloat16 bf16;
typedef __attribute__((ext_vector_type(8))) short s8v;    // 8 bf16 (4 VGPRs)
typedef __attribute__((ext_vector_type(4))) float f4v;    // MFMA C/D

__device__ __forceinline__ f4v mfma_bf16(s8v a, s8v b, f4v c) {
  return __builtin_amdgcn_mfma_f32_16x16x32_bf16(a, b, c, 0, 0, 0);
}
__device__ __forceinline__ s8v ld8(const bf16* p) { return *(const s8v*)p; }
__device__ __forceinline__ float sigf(float x) { return 1.f / (1.f + expf(-x)); }
// fp32 -> bf16 bits, RNE
__device__ __forceinline__ short f2bs(float f) {
  union { float f; unsigned u; } c; c.f = f;
  unsigned u = c.u + 0x7fff + ((c.u >> 16) & 1);
  return (short)(u >> 16);
}

// ============ one-time: fp32 [N,1024] -> bf16 MFMA-frag blob ============
// blob[((nt*32+kc)*64 + lane)*8 + j]; n = nt*16+(lane&15), k = kc*32+(lane>>4)*8+j
__global__ __launch_bounds__(256) void shuffle_w(const float* __restrict__ src,
                                                 bf16* __restrict__ dst, int ngroups) {
  int g = blockIdx.x * 256 + threadIdx.x;
  if (g >= ngroups) return;
  int lane = g & 63, kc = (g >> 6) & 31, nt = g >> 11;
  int n = nt * 16 + (lane & 15);
  int k = kc * 32 + ((lane >> 4) << 3);
  const float* s = src + (size_t)n * HDIM + k;
  short* d = (short*)dst + (size_t)g * 8;
  s8v v;
#pragma unroll
  for (int j = 0; j < 8; ++j) v[j] = f2bs(s[j]);
  *(s8v*)d = v;
}

// ============ one-time fp32 tile GEMM: C = [relu](A[M,K] @ W[N,K]^T + bias [+bias2 if n<lim]) ============
struct GemmArgs {
  const float* A; const float* W; const float* bias; const float* bias2;
  float* C; int ldc; int K; int reluA; int reluC; int b2lim;
};
#define LDP 68
__global__ __launch_bounds__(256) void gemm_bt(GemmArgs g) {
  __shared__ float As[16][LDP];
  __shared__ float Ws[16][LDP];
  const int tid = threadIdx.x;
  const int tx = tid & 15, ty = tid >> 4;
  const int m0 = blockIdx.y * 64, n0 = blockIdx.x * 64;
  float acc[4][4] = {{0.f, 0.f, 0.f, 0.f}};
  const int K = g.K;
  for (int kb = 0; kb < K / 16; ++kb) {
    const int k0 = kb * 16;
#pragma unroll
    for (int i = 0; i < 4; ++i) {
      int idx = tid + i * 256;
      int ml = idx >> 4, kl = idx & 15;
      float a = g.A[(size_t)(m0 + ml) * K + k0 + kl];
      if (g.reluA) a = fmaxf(a, 0.f);
      As[kl][ml] = a;
      Ws[kl][ml] = g.W[(size_t)(n0 + ml) * K + k0 + kl];
    }
    __syncthreads();
#pragma unroll
    for (int k = 0; k < 16; ++k) {
      float4 av = *(const float4*)&As[k][ty * 4];
      float4 wv = *(const float4*)&Ws[k][tx * 4];
      float a[4] = {av.x, av.y, av.z, av.w};
      float w[4] = {wv.x, wv.y, wv.z, wv.w};
#pragma unroll
      for (int i = 0; i < 4; ++i)
#pragma unroll
        for (int j = 0; j < 4; ++j)
          acc[i][j] = fmaf(a[i], w[j], acc[i][j]);
    }
    __syncthreads();
  }
#pragma unroll
  for (int i = 0; i < 4; ++i) {
    int m = m0 + ty * 4 + i;
#pragma unroll
    for (int j = 0; j < 4; ++j) {
      int n = n0 + tx * 4 + j;
      float v = acc[i][j] + g.bias[n];
      if (g.bias2 && n < g.b2lim) v += g.bias2[n];
      if (g.reluC) v = fmaxf(v, 0.f);
      g.C[(size_t)m * g.ldc + n] = v;
    }
  }
}

// ============ one-time: std [B,H] fp32 h -> lin fp32 (x2) and frag bf16 (x2) ============
// lin flat: ((blk*256+tid)*4 + r); blk=(b>>5)*32+(h>>5); w=((b>>4)&1)|(((h>>4)&1)<<1);
//           quad=(b>>2)&3; r=b&3; l15=h&15; tid=w*64+quad*16+l15
__global__ __launch_bounds__(256) void permute_lin(const float* __restrict__ s,
                                                   float* __restrict__ d0,
                                                   float* __restrict__ d1) {
  int flat = blockIdx.x * 256 + threadIdx.x;   // B*H threads
  int r = flat & 3, tid = (flat >> 2) & 255, blk = flat >> 10;
  int w = tid >> 6, quad = (tid >> 4) & 3, l15 = tid & 15;
  int b = ((blk >> 5) << 5) + ((w & 1) << 4) + (quad << 2) + r;
  int h = ((blk & 31) << 5) + ((w >> 1) << 4) + l15;
  float v = s[(size_t)b * HDIM + h];
  d0[flat] = v; d1[flat] = v;
}
__global__ __launch_bounds__(256) void permute_frag(const float* __restrict__ s,
                                                    bf16* __restrict__ d0,
                                                    bf16* __restrict__ d1) {
  int g = blockIdx.x * 256 + threadIdx.x;      // (B/16)*32*64 groups
  int lane = g & 63, kc = (g >> 6) & 31, mt = g >> 11;
  int m = mt * 16 + (lane & 15), k = kc * 32 + ((lane >> 4) << 3);
  const float* src = s + (size_t)m * HDIM + k;
  s8v v;
#pragma unroll
  for (int j = 0; j < 8; ++j) v[j] = f2bs(src[j]);
  *(s8v*)((short*)d0 + (size_t)g * 8) = v;
  *(s8v*)((short*)d1 + (size_t)g * 8) = v;
}

// ============ the per-step fused kernel ============
// launch k: blocks 0..255 layer0(t=k) | 256..511 layer1(t=k-1) | 512..519 outproj(t=k-2)
struct StepArgs {
  int k;
  const int* target;
  const float* table;          // [V,3H] = relu(emb)@Wih0^T + b_ih0 + b_hh0(r,z only)
  const bf16* Whh0;            // frag blob, 3072 rows
  const float* bhh0n;          // b_hh0 + 2048
  const bf16* h0f_in; const float* h0l_in;
  bf16* h0f_out;      float* h0l_out;
  const bf16* Wih1; const bf16* Whh1;
  const float* bih1; const float* bhh1;
  const bf16* h1f_in; const float* h1l_in;   // H1[k-1]
  bf16* h1f_out;      float* h1l_out;        // H1[k]
  const bf16* Wof; const float* bo;
  float* out;
};

__global__ __launch_bounds__(256) void step_fused(StepArgs g) {
  __shared__ float logits[32][512];          // 64 KB, used by outproj role only
  const int blk = blockIdx.x;
  const int tid = threadIdx.x;
  const int w = tid >> 6, ln = tid & 63, l15 = ln & 15, quad = ln >> 4;

  if (blk < 256) {
    // ---- layer 0, t = k ----
    if (g.k > 255) return;
    const int m0 = (blk >> 5) << 5, n0 = (blk & 31) << 5;
    const int mt = m0 + ((w & 1) << 4), nt = n0 + ((w >> 1) << 4);
    const int MT = mt >> 4, NT = nt >> 4;
    const bf16* pA = g.h0f_in + ((size_t)MT * 32) * 512 + ln * 8;
    const bf16* pb0 = g.Whh0 + ((size_t)NT * 32) * 512 + ln * 8;
    const bf16* pb1 = g.Whh0 + ((size_t)(64 + NT) * 32) * 512 + ln * 8;
    const bf16* pb2 = g.Whh0 + ((size_t)(128 + NT) * 32) * 512 + ln * 8;
    f4v a0 = {0.f, 0.f, 0.f, 0.f}, a1 = a0, a2 = a0;
#pragma unroll 4
    for (int kc = 0; kc < 32; ++kc) {
      s8v A = ld8(pA + kc * 512);
      a0 = mfma_bf16(A, ld8(pb0 + kc * 512), a0);
      a1 = mfma_bf16(A, ld8(pb1 + kc * 512), a1);
      a2 = mfma_bf16(A, ld8(pb2 + kc * 512), a2);
    }
    const int n = nt + l15;
    const float bhn = g.bhh0n[n];
    float4 hp4 = *(const float4*)(g.h0l_in + (((size_t)blk << 8) + tid) * 4);
    float hp[4] = {hp4.x, hp4.y, hp4.z, hp4.w};
    float hv[4];
#pragma unroll
    for (int r = 0; r < 4; ++r) {
      int m = mt + (quad << 2) + r;
      int tok = (g.k == 0) ? 0 : g.target[m * TLEN + g.k - 1];
      const float* trow = g.table + (size_t)tok * H3;
      float rr = sigf(trow[n] + a0[r]);
      float zz = sigf(trow[n + 1024] + a1[r]);
      float nn = tanhf(trow[n + 2048] + rr * (a2[r] + bhn));
      hv[r] = (1.f - zz) * nn + zz * hp[r];
    }
    *(float4*)(g.h0l_out + (((size_t)blk << 8) + tid) * 4) =
        make_float4(hv[0], hv[1], hv[2], hv[3]);
    // frag write: value (m, k=n): lane' = (m&15) + 16*((n&31)>>3), j' = n&7
    const int kc2 = n >> 5;
    const int lhigh = (((nt >> 4) & 1) << 1) + (l15 >> 3);
    const int jp = l15 & 7;
    short* fo = (short*)g.h0f_out + (((size_t)(MT * 32 + kc2)) << 9) + jp;
#pragma unroll
    for (int r = 0; r < 4; ++r) {
      int lanep = (quad << 2) + r + (lhigh << 4);
      fo[lanep * 8] = f2bs(hv[r]);
    }
  } else if (blk < 512) {
    // ---- layer 1, t = k-1 ----
    if (g.k < 1 || g.k > 256) return;
    const int b1 = blk - 256;
    const int m0 = (b1 >> 5) << 5, n0 = (b1 & 31) << 5;
    const int mt = m0 + ((w & 1) << 4), nt = n0 + ((w >> 1) << 4);
    const int MT = mt >> 4, NT = nt >> 4;
    const bf16* pAx = g.h0f_in + ((size_t)MT * 32) * 512 + ln * 8;  // x = H0[k]
    const bf16* pAh = g.h1f_in + ((size_t)MT * 32) * 512 + ln * 8;
    const bf16* pir = g.Wih1 + ((size_t)NT * 32) * 512 + ln * 8;
    const bf16* piz = g.Wih1 + ((size_t)(64 + NT) * 32) * 512 + ln * 8;
    const bf16* pin = g.Wih1 + ((size_t)(128 + NT) * 32) * 512 + ln * 8;
    const bf16* phr = g.Whh1 + ((size_t)NT * 32) * 512 + ln * 8;
    const bf16* phz = g.Whh1 + ((size_t)(64 + NT) * 32) * 512 + ln * 8;
    const bf16* phn = g.Whh1 + ((size_t)(128 + NT) * 32) * 512 + ln * 8;
    f4v ar = {0.f, 0.f, 0.f, 0.f}, az = ar, ain = ar, ahn = ar;
#pragma unroll 2
    for (int kc = 0; kc < 32; ++kc) {
      s8v Ax = ld8(pAx + kc * 512);
      s8v Ah = ld8(pAh + kc * 512);
      ar = mfma_bf16(Ax, ld8(pir + kc * 512), ar);
      ar = mfma_bf16(Ah, ld8(phr + kc * 512), ar);
      az = mfma_bf16(Ax, ld8(piz + kc * 512), az);
      az = mfma_bf16(Ah, ld8(phz + kc * 512), az);
      ain = mfma_bf16(Ax, ld8(pin + kc * 512), ain);
      ahn = mfma_bf16(Ah, ld8(phn + kc * 512), ahn);
    }
    const int n = nt + l15;
    const float br = g.bih1[n] + g.bhh1[n];
    const float bz = g.bih1[n + 1024] + g.bhh1[n + 1024];
    const float bin = g.bih1[n + 2048], bhn = g.bhh1[n + 2048];
    float4 hp4 = *(const float4*)(g.h1l_in + (((size_t)b1 << 8) + tid) * 4);
    float hp[4] = {hp4.x, hp4.y, hp4.z, hp4.w};
    float hv[4];
#pragma unroll
    for (int r = 0; r < 4; ++r) {
      float rr = sigf(ar[r] + br);
      float zz = sigf(az[r] + bz);
      float nn = tanhf(ain[r] + bin + rr * (ahn[r] + bhn));
      hv[r] = (1.f - zz) * nn + zz * hp[r];
    }
    *(float4*)(g.h1l_out + (((size_t)b1 << 8) + tid) * 4) =
        make_float4(hv[0], hv[1], hv[2], hv[3]);
    const int kc2 = n >> 5;
    const int lhigh = (((nt >> 4) & 1) << 1) + (l15 >> 3);
    const int jp = l15 & 7;
    short* fo = (short*)g.h1f_out + (((size_t)(MT * 32 + kc2)) << 9) + jp;
#pragma unroll
    for (int r = 0; r < 4; ++r) {
      int lanep = (quad << 2) + r + (lhigh << 4);
      fo[lanep * 8] = f2bs(hv[r]);
    }
  } else {
    // ---- output projection + log_softmax, t = k-2 ----
    if (g.k < 2) return;
    const int to = g.k - 2;
    const int b0 = (blk - 512) * 32;
    const int MT = (b0 >> 4) + (w & 1);
    const int nb = (w >> 1) << 8;             // 0 or 256
    const bf16* pA = g.h1f_in + ((size_t)MT * 32) * 512 + ln * 8;  // H1[k-1]
#pragma unroll
    for (int nh = 0; nh < 2; ++nh) {
      f4v acc[8];
#pragma unroll
      for (int u = 0; u < 8; ++u) acc[u] = (f4v){0.f, 0.f, 0.f, 0.f};
      const int NTb = (nb + nh * 128) >> 4;
      for (int kc = 0; kc < 32; ++kc) {
        s8v A = ld8(pA + kc * 512);
#pragma unroll
        for (int u = 0; u < 8; ++u) {
          s8v B = ld8(g.Wof + (((size_t)(NTb + u) * 32 + kc) << 9) + ln * 8);
          acc[u] = mfma_bf16(A, B, acc[u]);
        }
      }
#pragma unroll
      for (int u = 0; u < 8; ++u) {
        int col = nb + nh * 128 + u * 16 + l15;
        float bov = g.bo[col];
#pragma unroll
        for (int r = 0; r < 4; ++r) {
          int row = ((w & 1) << 4) + (quad << 2) + r;
          logits[row][col] = acc[u][r] + bov;
        }
      }
    }
    __syncthreads();
    // softmax: 8 threads per row
    const int row = tid >> 3, s = tid & 7;
    float mx = -1e30f;
    for (int v = s; v < 512; v += 8) mx = fmaxf(mx, logits[row][v]);
#pragma unroll
    for (int o = 4; o > 0; o >>= 1) mx = fmaxf(mx, __shfl_xor(mx, o));
    float sum = 0.f;
    for (int v = s; v < 512; v += 8) sum += expf(logits[row][v] - mx);
#pragma unroll
    for (int o = 4; o > 0; o >>= 1) sum += __shfl_xor(sum, o);
    float lse = mx + logf(sum);
    float* orow = g.out + ((size_t)(b0 + row) * TLEN + to) * VDIM;
    for (int v = s; v < 512; v += 8) orow[v] = logits[row][v] - lse;
  }
}

// ============ final: un-permute lin h -> h_final [2,B,H] ============
__global__ __launch_bounds__(256) void unperm_hfinal(const float* __restrict__ h0l,
                                                     const float* __restrict__ h1l,
                                                     float* __restrict__ out) {
  int idx = blockIdx.x * 256 + threadIdx.x;   // 2*B*H
  const int BH = BATCH * HDIM;
  int layer = idx >= BH ? 1 : 0;
  int e = idx - layer * BH;
  int b = e >> 10, h = e & 1023;
  int blk = ((b >> 5) << 5) + (h >> 5);
  int w = ((b >> 4) & 1) + (((h >> 4) & 1) << 1);
  int quad = (b >> 2) & 3, r = b & 3, l15 = h & 15;
  int tid = (w << 6) + (quad << 4) + l15;
  int flat = ((blk << 8) + tid) * 4 + r;
  out[idx] = layer ? h1l[flat] : h0l[flat];
}

extern "C" void kernel_launch(void* const* d_in, const int* in_sizes, int n_in,
                              void* d_out, int out_size, void* d_ws, size_t ws_size,
                              hipStream_t stream) {
  const float* fps    = (const float*)d_in[1];
  const int* target   = (const int*)d_in[2];
  const float* emb    = (const float*)d_in[3];
  const float* Wc     = (const float*)d_in[4];
  const float* bc     = (const float*)d_in[5];
  const float* W_ih   = (const float*)d_in[6];   // [2,3H,H]
  const float* W_hh   = (const float*)d_in[7];
  const float* b_ih   = (const float*)d_in[8];
  const float* b_hh   = (const float*)d_in[9];
  const float* Wo     = (const float*)d_in[10];
  const float* bo     = (const float*)d_in[11];
  float* out = (float*)d_out;

  const int BH = BATCH * HDIM;
  const size_t WN = (size_t)H3 * HDIM;

  char* p = (char*)d_ws;
  float* hstd  = (float*)p; p += (size_t)BH * 4;
  float* table = (float*)p; p += (size_t)VDIM * H3 * 4;
  float* H0l[2]; H0l[0] = (float*)p; p += (size_t)BH * 4; H0l[1] = (float*)p; p += (size_t)BH * 4;
  float* H1l[2]; H1l[0] = (float*)p; p += (size_t)BH * 4; H1l[1] = (float*)p; p += (size_t)BH * 4;
  bf16* H0f[2]; H0f[0] = (bf16*)p; p += (size_t)BH * 2; H0f[1] = (bf16*)p; p += (size_t)BH * 2;
  bf16* H1f[2]; H1f[0] = (bf16*)p; p += (size_t)BH * 2; H1f[1] = (bf16*)p; p += (size_t)BH * 2;
  bf16* Whh0f = (bf16*)p; p += WN * 2;
  bf16* Wih1f = (bf16*)p; p += WN * 2;
  bf16* Whh1f = (bf16*)p; p += WN * 2;
  bf16* Wof   = (bf16*)p; p += (size_t)VDIM * HDIM * 2;

  // one-time weight shuffles into fragment blobs
  {
    int ng3 = (H3 / 16) * 32 * 64;             // 393216
    shuffle_w<<<ng3 / 256, 256, 0, stream>>>(W_hh, Whh0f, ng3);
    shuffle_w<<<ng3 / 256, 256, 0, stream>>>(W_ih + WN, Wih1f, ng3);
    shuffle_w<<<ng3 / 256, 256, 0, stream>>>(W_hh + WN, Whh1f, ng3);
    int ngv = (VDIM / 16) * 32 * 64;           // 65536
    shuffle_w<<<ngv / 256, 256, 0, stream>>>(Wo, Wof, ngv);
  }
  // init hidden: hstd = relu(fps @ Wc^T + bc)
  {
    GemmArgs a; a.A = fps; a.W = Wc; a.bias = bc; a.bias2 = nullptr;
    a.C = hstd; a.ldc = HDIM; a.K = FPDIM; a.reluA = 0; a.reluC = 1; a.b2lim = 0;
    gemm_bt<<<dim3(HDIM / 64, BATCH / 64), 256, 0, stream>>>(a);
  }
  // gi0 table = relu(emb) @ Wih0^T + b_ih0 + b_hh0 (r,z parts only)
  {
    GemmArgs a; a.A = emb; a.W = W_ih; a.bias = b_ih; a.bias2 = b_hh;
    a.C = table; a.ldc = H3; a.K = HDIM; a.reluA = 1; a.reluC = 0; a.b2lim = 2048;
    gemm_bt<<<dim3(H3 / 64, VDIM / 64), 256, 0, stream>>>(a);
  }
  // permute init hidden into lin + frag (H0[0], H1[0] -> parity-0 buffers)
  permute_lin<<<BH / 256, 256, 0, stream>>>(hstd, H0l[0], H1l[0]);
  permute_frag<<<(BATCH / 16) * 32 * 64 / 256, 256, 0, stream>>>(hstd, H0f[0], H1f[0]);

  // pipelined step loop: launch k does layer0(k) | layer1(k-1) | outproj(k-2)
  for (int k = 0; k <= TLEN + 1; ++k) {
    StepArgs s;
    s.k = k; s.target = target; s.table = table;
    s.Whh0 = Whh0f; s.bhh0n = b_hh + 2048;
    s.h0f_in = H0f[k & 1];         s.h0l_in = H0l[k & 1];
    s.h0f_out = H0f[(k + 1) & 1];  s.h0l_out = H0l[(k + 1) & 1];
    s.Wih1 = Wih1f; s.Whh1 = Whh1f;
    s.bih1 = b_ih + H3; s.bhh1 = b_hh + H3;
    s.h1f_in = H1f[(k + 1) & 1];   s.h1l_in = H1l[(k + 1) & 1];  // H1[k-1]
    s.h1f_out = H1f[k & 1];        s.h1l_out = H1l[k & 1];        // H1[k]
    s.Wof = Wof; s.bo = bo; s.out = out;
    step_fused<<<520, 256, 0, stream>>>(s);
  }

  // h_final = [H0[256], H1[256]] (both land in parity-0 buffers)
  unperm_hfinal<<<2 * BH / 256, 256, 0, stream>>>(H0l[0], H1l[0],
                                                  out + (size_t)BATCH * TLEN * VDIM);
}